// Round 3
// baseline (2743.922 us; speedup 1.0000x reference)
//
#include <hip/hip_runtime.h>

#define NB   8
#define NP   8192
#define NS   2048
#define NK   16
#define DIN  64
#define DOUT 128
#define BN_EPS 1e-5f

#define MT   512            // mega-kernel block size
#define NW   248            // worker blocks (grid = 8 fps + 248 workers = 256 CUs)
#define FP   (NP / MT)      // 16 fps points per thread
#define FW   (MT / 64)      // 8 waves
#define KJ   (NP / MT)      // 16 knn points per thread
#define KBINS 64
#define MAXC 512

typedef unsigned long long ull;

// ---------------- K0: fold BN into weights, transpose to [k][o] ----------------
__global__ void fold_weights_kernel(const float* __restrict__ W, const float* __restrict__ bias,
                                    const float* __restrict__ gamma, const float* __restrict__ beta,
                                    const float* __restrict__ rmean, const float* __restrict__ rvar,
                                    float* __restrict__ Wt, float* __restrict__ Cb)
{
    int i = blockIdx.x * 256 + threadIdx.x;
    if (i < DIN * DOUT) {
        int o = i & (DOUT - 1);
        int k = i >> 7;
        float sc = gamma[o] * rsqrtf(rvar[o] + BN_EPS);
        Wt[i] = W[o * DIN + k] * sc;            // Wt[k*128 + o]
        if (i < DOUT) {
            Cb[i] = (bias[i] - rmean[i]) * sc + beta[i];
        }
    }
}

// ---------------- f64-packed argmax helpers --------------------------------------
// packed u64 = (fp32 dist bits << 32) | ~idx, as double (sign bit 0 -> numeric
// order == u64 order): fmax == (max dist, tie -> min idx).
template<int CTRL, int RMASK>
__device__ __forceinline__ double dpp_max_f64(double v)
{
    unsigned long long u = (unsigned long long)__double_as_longlong(v);
    unsigned hi = (unsigned)(u >> 32), lo = (unsigned)u;
    unsigned th = (unsigned)__builtin_amdgcn_update_dpp((int)hi, (int)hi, CTRL, RMASK, 0xF, false);
    unsigned tl = (unsigned)__builtin_amdgcn_update_dpp((int)lo, (int)lo, CTRL, RMASK, 0xF, false);
    double o = __longlong_as_double((long long)(((unsigned long long)th << 32) | tl));
    return fmax(v, o);
}

__device__ __forceinline__ float max3f(float a, float b, float c)
{
    return fmaxf(fmaxf(a, b), c);   // clang fuses to v_max3_f32 (exact, associative)
}

__device__ __forceinline__ int knn_bin(float d)
{
    int e = (int)(__float_as_uint(d) >> 23) - 90;   // monotone, clamped octave bins
    return e < 0 ? 0 : (e > 63 ? 63 : e);
}

// coarse 8x8x8 morton cell over [-4,4]^3 (clamped; N(0,1) data)
__device__ __forceinline__ unsigned cell9(float x, float y, float z)
{
    int a = (int)(x + 4.0f); a = a < 0 ? 0 : (a > 7 ? 7 : a);
    int b = (int)(y + 4.0f); b = b < 0 ? 0 : (b > 7 ? 7 : b);
    int c = (int)(z + 4.0f); c = c < 0 ? 0 : (c > 7 ? 7 : c);
    return (unsigned)((a & 1) | ((b & 1) << 1) | ((c & 1) << 2)
         | (((a >> 1) & 1) << 3) | (((b >> 1) & 1) << 4) | (((c >> 1) & 1) << 5)
         | (((a >> 2) & 1) << 6) | (((b >> 2) & 1) << 7) | (((c >> 2) & 1) << 8));
}

// ---------------- mega kernel: 8 fps producers + 248 persistent workers --------
struct FpsS {
    float4 sxyz[NP];                    // morton-sorted, w = orig idx bits (128 KB)
    float4 selring[64];                 // selection-coords ring, slot = n & 63.
    // 64-deep so the winner-push of selection s+1 (slot (s+1)&63) can never
    // collide with the granule publish at step s reading slots (s-31..s)&63:
    // the publish half and the push slot are in opposite 32-slot halves.
    float4 bc;                          // current-centroid broadcast slot
    unsigned long long rv64[2][FW];
    unsigned hist[512];                 // counting-sort bins / running bases
    unsigned wsum[FW];
};
struct KnnS {
    float sdist[NP];                    // 32 KB
    unsigned hist[KBINS][33];           // [bin][c] +pad: atomic bank=(bin+c)%32, conflict-free
    float cd[MAXC];
    int   ci[MAXC];
    int   sidx[NK];
    float sf[NK][DIN];                  // 4 KB gathered feat rows
    float red[4][DOUT];                 // 2 KB cross-group max
    unsigned ccnt;
    int cut;
};
union MegaS { FpsS f; KnnS k; };
// union = ~131 KB -> 1 block/CU; grid 256 -> all blocks co-resident,
// so producer progress never depends on dispatch order (deadlock-safe).

__global__ __launch_bounds__(MT, 1)
void mega_kernel(const float* __restrict__ coords, float* __restrict__ out_coords,
                 const float* __restrict__ feat, const float* __restrict__ Wt,
                 const float* __restrict__ Cb, float* __restrict__ outF,
                 unsigned* __restrict__ flags)
{
#pragma clang fp contract(off)
    __shared__ MegaS smem;
    const int t = threadIdx.x;

    if (blockIdx.x < NB) {
        // ================= FPS producer (1 block per batch) =================
        // Exact triangle-inequality pruning: thread owns 16 morton-contiguous
        // points (center ctr, radius rad). Skip the 16-pt min-update iff
        // |c-ctr| >= rad + sqrt(max dist in chunk)  (with 4e-4 rel margin, so
        // a skip is provably a no-op -> selections bit-identical to unpruned).
        const int b = blockIdx.x;
        const float* cb = coords + (size_t)b * NP * 3;
        const int wave = t >> 6, lane = t & 63;

        // ---- counting sort by morton cell ----
        smem.f.hist[t] = 0;
        __syncthreads();
        unsigned mycell[FP];
#pragma unroll
        for (int k = 0; k < FP; ++k) {
            int i = t + k * MT;
            float x = cb[i * 3 + 0], y = cb[i * 3 + 1], z = cb[i * 3 + 2];
            unsigned mc = cell9(x, y, z);
            mycell[k] = mc;
            atomicAdd(&smem.f.hist[mc], 1u);
        }
        __syncthreads();
        {   // exclusive scan over 512 bins: wave scan + cross-wave offsets
            unsigned v = smem.f.hist[t];
            unsigned incl = v;
#pragma unroll
            for (int off = 1; off < 64; off <<= 1) {
                unsigned n = __shfl_up(incl, off);
                if (lane >= off) incl += n;
            }
            if (lane == 63) smem.f.wsum[wave] = incl;
            __syncthreads();
            unsigned wadd = 0;
#pragma unroll
            for (int w = 0; w < FW; ++w) wadd += (w < wave) ? smem.f.wsum[w] : 0;
            smem.f.hist[t] = wadd + incl - v;       // own slot only: no race with v-reads
            __syncthreads();
        }
#pragma unroll
        for (int k = 0; k < FP; ++k) {              // scatter to sorted order
            int i = t + k * MT;
            float x = cb[i * 3 + 0], y = cb[i * 3 + 1], z = cb[i * 3 + 2];
            unsigned pos = atomicAdd(&smem.f.hist[mycell[k]], 1u);
            smem.f.sxyz[pos] = make_float4(x, y, z, __uint_as_float((unsigned)i));
            if (i == 0) {                           // selection 0 = orig point 0
                smem.f.bc = make_float4(x, y, z, 0.0f);
                smem.f.selring[0] = make_float4(x, y, z, 0.0f);
            }
        }
        __syncthreads();

        // ---- load chunk [16t, 16t+16), compute center + (inflated) radius ----
        float px[FP], py[FP], pz[FP], dist[FP];
        unsigned no[FP];                            // ~orig_idx per point
        float sx = 0.f, sy = 0.f, sz = 0.f;
#pragma unroll
        for (int k = 0; k < FP; ++k) {
            float4 p = smem.f.sxyz[t * FP + k];
            px[k] = p.x; py[k] = p.y; pz[k] = p.z;
            no[k] = ~__float_as_uint(p.w);
            dist[k] = 1e10f;
            sx += p.x; sy += p.y; sz += p.z;
        }
        const float ctrx = sx * (1.0f / FP), ctry = sy * (1.0f / FP), ctrz = sz * (1.0f / FP);
        float r2m = 0.f;
#pragma unroll
        for (int k = 0; k < FP; ++k) {
            float dx = px[k] - ctrx, dy = py[k] - ctry, dz = pz[k] - ctrz;
            r2m = fmaxf(r2m, fmaf(dz, dz, fmaf(dy, dy, dx * dx)));
        }
        const float rad = sqrtf(r2m) * 1.0001f + 1e-6f;   // certified upper bound

        float R2 = 3.4e38f;                 // force recompute at s=0
        ull mypack = 0, wavepack = 0;
        float cx = smem.f.bc.x, cy = smem.f.bc.y, cz = smem.f.bc.z;

        for (int s = 0; s < NS; ++s) {
            float ddx = ctrx - cx, ddy = ctry - cy, ddz = ctrz - cz;
            float dc2 = fmaf(ddz, ddz, fmaf(ddy, ddy, ddx * ddx));
            bool need = dc2 < R2;

            if (need) {
#pragma unroll
                for (int k = 0; k < FP; ++k) {
                    float dx = px[k] - cx, dy = py[k] - cy, dz = pz[k] - cz;
                    float d = fmaf(dz, dz, fmaf(dy, dy, dx * dx));
                    dist[k] = fminf(dist[k], d);
                }
                float a0 = max3f(dist[0],  dist[1],  dist[2]);
                float a1 = max3f(dist[3],  dist[4],  dist[5]);
                float a2 = max3f(dist[6],  dist[7],  dist[8]);
                float a3 = max3f(dist[9],  dist[10], dist[11]);
                float a4 = max3f(dist[12], dist[13], dist[14]);
                float m  = fmaxf(max3f(a0, a1, a2), max3f(a3, a4, dist[15]));
                unsigned lo = 0;                    // max ~idx == min orig idx at m
#pragma unroll
                for (int k = 0; k < FP; ++k) {
                    unsigned cand = lo > no[k] ? lo : no[k];
                    lo = (dist[k] == m) ? cand : lo;
                }
                mypack = ((ull)__float_as_uint(m) << 32) | lo;
                float rs = rad + sqrtf(m);
                R2 = rs * rs * 1.0004f + 1e-6f;     // conservative skip bound
            }

            double best = __longlong_as_double((long long)mypack);
            ull wb = __ballot(need);
            if (wb) {                               // wave-uniform branch
                best = dpp_max_f64<0xB1,  0xF>(best);  // quad_perm xor1
                best = dpp_max_f64<0x4E,  0xF>(best);  // quad_perm xor2
                best = dpp_max_f64<0x124, 0xF>(best);  // row_ror:4
                best = dpp_max_f64<0x128, 0xF>(best);  // row_ror:8
                best = dpp_max_f64<0x142, 0xA>(best);  // row_bcast15
                best = dpp_max_f64<0x143, 0xC>(best);  // row_bcast31
                if (lane == 63) wavepack = (ull)__double_as_longlong(best);
            }
            int pb = s & 1;
            if (lane == 63) smem.f.rv64[pb][wave] = wavepack;
            __syncthreads();

            // cross-wave: b64 read of partial[lane&7], 4 DPP levels over row-of-16
            double g = __longlong_as_double((long long)smem.f.rv64[pb][lane & 7]);
            g = dpp_max_f64<0xB1,  0xF>(g);
            g = dpp_max_f64<0x4E,  0xF>(g);
            g = dpp_max_f64<0x124, 0xF>(g);
            g = dpp_max_f64<0x128, 0xF>(g);
            ull gp = (ull)__double_as_longlong(g);

            // winner (unique: pack low = ~orig_idx) pushes next centroid coords
            if (mypack == gp) {
                unsigned wlo = (unsigned)gp;
                int kk = 0;
#pragma unroll
                for (int k = FP - 1; k >= 0; --k)
                    if (no[k] == wlo) kk = k;
                float4 w4 = make_float4(px[kk], py[kk], pz[kk], 0.0f);
                smem.f.bc = w4;
                if (s + 1 < NS) smem.f.selring[(s + 1) & 63] = w4;
            }
            __syncthreads();
            cx = smem.f.bc.x; cy = smem.f.bc.y; cz = smem.f.bc.z;

            // publish a 32-query granule (wave 0: program-order release covers
            // the wave's own coord stores)
            if ((s & 31) == 31) {
                int base = s - 31;                  // slots (base&63)..(base&63)+31
                if (t < 32) {
                    float4 p = smem.f.selring[(base & 63) + t];
                    float* dst = out_coords + ((size_t)b * NS + base + t) * 3;
                    dst[0] = p.x; dst[1] = p.y; dst[2] = p.z;
                }
                if (t == 0)
                    __hip_atomic_store(&flags[b * 16], (unsigned)((s + 1) >> 5),
                                       __ATOMIC_RELEASE, __HIP_MEMORY_SCOPE_AGENT);
            }
        }
    } else {
        // ===== persistent worker: knn + fused gather/MLP/max per query =====
        const int wid = blockIdx.x - NB;           // 0..247
        const int c = t & 31;
        const int o = t & (DOUT - 1);
        const int grp = t >> 7;                    // 0..3
        const int lane = t & 63;

        for (int j = wid; j < NB * NS; j += NW) {
            const int s = j >> 3, b = j & 7;       // ascending s per worker
            const int q = b * NS + s;

            if (t == 0) {
                const unsigned need = (unsigned)(s >> 5) + 1;
                while (__hip_atomic_load(&flags[b * 16], __ATOMIC_ACQUIRE,
                                         __HIP_MEMORY_SCOPE_AGENT) < need)
                    __builtin_amdgcn_s_sleep(32);
            }
            __syncthreads();

            const float* cb = coords + (size_t)b * NP * 3;
            const float* qp = out_coords + (size_t)q * 3;
            const float qx = qp[0], qy = qp[1], qz = qp[2];

            for (int i = t; i < KBINS * 33; i += MT) ((unsigned*)smem.k.hist)[i] = 0;
            if (t == 0) smem.k.ccnt = 0;
            __syncthreads();

            for (int jj = 0; jj < KJ; ++jj) {
                int i = t + jj * MT;
                float dx = cb[i * 3 + 0] - qx, dy = cb[i * 3 + 1] - qy, dz = cb[i * 3 + 2] - qz;
                float d = fmaf(dz, dz, fmaf(dy, dy, dx * dx));
                smem.k.sdist[i] = d;
                atomicAdd(&smem.k.hist[knn_bin(d)][c], 1u);
            }
            __syncthreads();

            if (t < 64) {
                unsigned total = 0;
#pragma unroll
                for (int cc = 0; cc < 32; ++cc) total += smem.k.hist[t][cc];
                unsigned incl = total;
#pragma unroll
                for (int off = 1; off < 64; off <<= 1) {
                    unsigned n = __shfl_up(incl, off);
                    if (t >= off) incl += n;
                }
                unsigned excl = incl - total;
                if (excl < NK && incl >= NK) smem.k.cut = t;
            }
            __syncthreads();

            const int cut = smem.k.cut;
            for (int jj = 0; jj < KJ; ++jj) {
                int i = t + jj * MT;
                float d = smem.k.sdist[i];
                bool take = knn_bin(d) <= cut;
                unsigned long long mk = __ballot(take);
                unsigned base = 0;
                if (lane == 0 && mk)
                    base = atomicAdd(&smem.k.ccnt, (unsigned)__popcll(mk));
                base = __shfl(base, 0);
                if (take) {
                    unsigned p = base + (unsigned)__popcll(mk & ((1ull << lane) - 1ull));
                    if (p < MAXC) { smem.k.cd[p] = d; smem.k.ci[p] = i; }
                }
            }
            __syncthreads();

            // parallel rank-select: rank = #{(dj,ij) < (d,i)}; unique ranks -> LDS
            int cnt = (int)(smem.k.ccnt < (unsigned)MAXC ? smem.k.ccnt : (unsigned)MAXC);
            for (int p = t; p < cnt; p += MT) {
                float d = smem.k.cd[p]; int idx = smem.k.ci[p];
                int rank = 0;
                for (int jj = 0; jj < cnt; ++jj) {
                    float dj = smem.k.cd[jj]; int ij = smem.k.ci[jj];
                    rank += (dj < d || (dj == d && ij < idx)) ? 1 : 0;
                }
                if (rank < NK) smem.k.sidx[rank] = idx;
            }
            __syncthreads();

            // gather 16 neighbor feat rows (coalesced 256-B rows)
#pragma unroll
            for (int rr = 0; rr < 2; ++rr) {
                int row = (t >> 6) + rr * 8;       // 0..15
                smem.k.sf[row][t & 63] =
                    feat[((size_t)b * NP + smem.k.sidx[row]) * DIN + (t & 63)];
            }
            __syncthreads();

            // fused MLP+relu+max: each thread handles out-channel o, neighbors
            // {grp, grp+4, grp+8, grp+12}; cross-group max via LDS
            const float cb0 = Cb[o];
            float mx = -3.4e38f;
#pragma unroll
            for (int nn = 0; nn < 4; ++nn) {
                const float4* f4 = (const float4*)smem.k.sf[grp + nn * 4];
                float acc = cb0;
#pragma unroll
                for (int k4 = 0; k4 < DIN / 4; ++k4) {
                    float4 f = f4[k4];
                    acc = fmaf(f.x, Wt[(k4 * 4 + 0) * DOUT + o], acc);
                    acc = fmaf(f.y, Wt[(k4 * 4 + 1) * DOUT + o], acc);
                    acc = fmaf(f.z, Wt[(k4 * 4 + 2) * DOUT + o], acc);
                    acc = fmaf(f.w, Wt[(k4 * 4 + 3) * DOUT + o], acc);
                }
                mx = fmaxf(mx, fmaxf(acc, 0.0f));
            }
            smem.k.red[grp][o] = mx;
            __syncthreads();

            if (t < DOUT) {
                float v = fmaxf(fmaxf(smem.k.red[0][t], smem.k.red[1][t]),
                                fmaxf(smem.k.red[2][t], smem.k.red[3][t]));
                outF[(size_t)q * DOUT + t] = v;
            }
            __syncthreads();
        }
    }
}

extern "C" void kernel_launch(void* const* d_in, const int* in_sizes, int n_in,
                              void* d_out, int out_size, void* d_ws, size_t ws_size,
                              hipStream_t stream)
{
    const float* coords = (const float*)d_in[0];
    const float* feat   = (const float*)d_in[1];
    const float* W      = (const float*)d_in[2];
    const float* bias   = (const float*)d_in[3];
    const float* gamma  = (const float*)d_in[4];
    const float* beta   = (const float*)d_in[5];
    const float* rmean  = (const float*)d_in[6];
    const float* rvar   = (const float*)d_in[7];

    float* out_coords = (float*)d_out;                    // [8,2048,3]
    float* out_feat   = out_coords + (size_t)NB * NS * 3; // [8,2048,128]

    char* ws = (char*)d_ws;
    float*    Wt    = (float*)ws;                         // 32 KB
    float*    Cb    = (float*)(ws + 32768);               // 512 B
    unsigned* flags = (unsigned*)(ws + 40960);            // 8 flags, 64B apart

    hipMemsetAsync(flags, 0, 8 * 16 * sizeof(unsigned), stream);
    fold_weights_kernel<<<(DIN * DOUT + 255) / 256, 256, 0, stream>>>(
        W, bias, gamma, beta, rmean, rvar, Wt, Cb);
    mega_kernel<<<NB + NW, MT, 0, stream>>>(
        coords, out_coords, feat, Wt, Cb, out_feat, flags);
}

// Round 4
// 2141.458 us; speedup vs baseline: 1.2813x; 1.2813x over previous
//
#include <hip/hip_runtime.h>

#define NB   8
#define NP   8192
#define NS   2048
#define NK   16
#define DIN  64
#define DOUT 128
#define BN_EPS 1e-5f

#define MT   512            // mega-kernel block size
#define NW   248            // worker blocks (grid = 8 fps + 248 workers = 256 CUs)
#define PT   256            // producer ACTIVE threads (4 waves); waves 4-7 = publisher
#define FPP  (NP / PT)      // 32 fps points per active thread
#define PW   (PT / 64)      // 4 active waves
#define KJ   (NP / MT)      // 16 knn points per thread
#define KBINS 64
#define MAXC 512

typedef unsigned long long ull;

// ---------------- K0: fold BN into weights, transpose to [k][o] ----------------
__global__ void fold_weights_kernel(const float* __restrict__ W, const float* __restrict__ bias,
                                    const float* __restrict__ gamma, const float* __restrict__ beta,
                                    const float* __restrict__ rmean, const float* __restrict__ rvar,
                                    float* __restrict__ Wt, float* __restrict__ Cb)
{
    int i = blockIdx.x * 256 + threadIdx.x;
    if (i < DIN * DOUT) {
        int o = i & (DOUT - 1);
        int k = i >> 7;
        float sc = gamma[o] * rsqrtf(rvar[o] + BN_EPS);
        Wt[i] = W[o * DIN + k] * sc;            // Wt[k*128 + o]
        if (i < DOUT) {
            Cb[i] = (bias[i] - rmean[i]) * sc + beta[i];
        }
    }
}

// ---------------- f64-packed argmax helpers --------------------------------------
// packed u64 = (fp32 dist bits << 32) | ~idx, as double (sign bit 0 -> numeric
// order == u64 order): fmax == (max dist, tie -> min idx).
template<int CTRL, int RMASK>
__device__ __forceinline__ double dpp_max_f64(double v)
{
    unsigned long long u = (unsigned long long)__double_as_longlong(v);
    unsigned hi = (unsigned)(u >> 32), lo = (unsigned)u;
    unsigned th = (unsigned)__builtin_amdgcn_update_dpp((int)hi, (int)hi, CTRL, RMASK, 0xF, false);
    unsigned tl = (unsigned)__builtin_amdgcn_update_dpp((int)lo, (int)lo, CTRL, RMASK, 0xF, false);
    double o = __longlong_as_double((long long)(((unsigned long long)th << 32) | tl));
    return fmax(v, o);
}

__device__ __forceinline__ float max3f(float a, float b, float c)
{
    return fmaxf(fmaxf(a, b), c);   // clang fuses to v_max3_f32 (exact, associative)
}

__device__ __forceinline__ int knn_bin(float d)
{
    int e = (int)(__float_as_uint(d) >> 23) - 90;   // monotone, clamped octave bins
    return e < 0 ? 0 : (e > 63 ? 63 : e);
}

// ---------------- mega kernel: 8 fps producers + 248 persistent workers --------
struct FpsS {
    float4 sxyz[NP];                    // 128 KB, immutable after staging
    int sel[NS];                        // 8 KB
    unsigned long long rv64[2][PW];     // double-buffered wave partials
};
struct KnnS {
    float sdist[NP];                    // 32 KB
    unsigned hist[KBINS][33];           // [bin][c] +pad: atomic bank=(bin+c)%32, conflict-free
    float cd[MAXC];
    int   ci[MAXC];
    int   sidx[NK];
    float sf[NK][DIN];                  // 4 KB gathered feat rows
    float red[4][DOUT];                 // 2 KB cross-group max
    unsigned ccnt;
    int cut;
};
union MegaS { FpsS f; KnnS k; };
// union = ~136 KB -> 1 block/CU; grid 256 -> all blocks co-resident,
// so producer progress never depends on dispatch order (deadlock-safe).

__global__ __launch_bounds__(MT, 1)
void mega_kernel(const float* __restrict__ coords, float* __restrict__ out_coords,
                 const float* __restrict__ feat, const float* __restrict__ Wt,
                 const float* __restrict__ Cb, float* __restrict__ outF,
                 unsigned* __restrict__ flags)
{
#pragma clang fp contract(off)
    __shared__ MegaS smem;
    const int t = threadIdx.x;

    if (blockIdx.x < NB) {
        // ================= FPS producer (1 block per batch) =================
        // 4 waves (256 threads, 32 pts each) run the serial FPS loop; waves 4-7
        // are a dedicated publisher (every-32-step granule export + flag), off
        // the critical waves. One barrier per step, counts match across roles.
        const int b = blockIdx.x;
        const float* cb = coords + (size_t)b * NP * 3;

        for (int i = t; i < NP; i += MT)
            smem.f.sxyz[i] = make_float4(cb[i * 3 + 0], cb[i * 3 + 1], cb[i * 3 + 2], 0.0f);
        __syncthreads();

        if (t < PT) {
            // ---------------- active FPS waves ----------------
            const int wave = t >> 6, lane = t & 63;
            const unsigned nt = ~(unsigned)t;      // ~(t + k*PT) == nt - (k<<8)

            float px[FPP], py[FPP], pz[FPP], dist[FPP];
#pragma unroll
            for (int k = 0; k < FPP; ++k) {
                float4 p = smem.f.sxyz[t + k * PT];
                px[k] = p.x; py[k] = p.y; pz[k] = p.z;
                dist[k] = 1e10f;
            }
            int cur = 0;

            for (int s = 0; s < NS; ++s) {
                if (t == 0) smem.f.sel[s] = cur;
                const float4 cc = smem.f.sxyz[cur];
                const float cx = cc.x, cy = cc.y, cz = cc.z;

                // min-dist update over 32 register-resident points
#pragma unroll
                for (int k = 0; k < FPP; ++k) {
                    float dx = px[k] - cx, dy = py[k] - cy, dz = pz[k] - cz;
                    float d = fmaf(dz, dz, fmaf(dy, dy, dx * dx));
                    dist[k] = fminf(dist[k], d);
                }
                // max of 32 via v_max3 tree (exact; max associative)
                float a0 = max3f(dist[0],  dist[1],  dist[2]);
                float a1 = max3f(dist[3],  dist[4],  dist[5]);
                float a2 = max3f(dist[6],  dist[7],  dist[8]);
                float a3 = max3f(dist[9],  dist[10], dist[11]);
                float a4 = max3f(dist[12], dist[13], dist[14]);
                float a5 = max3f(dist[15], dist[16], dist[17]);
                float a6 = max3f(dist[18], dist[19], dist[20]);
                float a7 = max3f(dist[21], dist[22], dist[23]);
                float a8 = max3f(dist[24], dist[25], dist[26]);
                float a9 = max3f(dist[27], dist[28], dist[29]);
                float u0 = max3f(a0, a1, a2);
                float u1 = max3f(a3, a4, a5);
                float u2 = max3f(a6, a7, a8);
                float v  = max3f(u0, u1, u2);
                float m  = max3f(v, a9, fmaxf(dist[30], dist[31]));

                // smallest k attaining m: two independent descending chains
                int kA = 99, kB = 99;
#pragma unroll
                for (int k = 15; k >= 0; --k)
                    if (dist[k] == m) kA = k;
#pragma unroll
                for (int k = 31; k >= 16; --k)
                    if (dist[k] == m) kB = k;
                const int kk = (kA != 99) ? kA : kB;
                double best = __longlong_as_double(
                    (long long)(((ull)__float_as_uint(m) << 32) | (nt - (unsigned)(kk << 8))));

                // wave argmax: 6 DPP f64-max levels -> lane 63 holds wave max
                best = dpp_max_f64<0xB1,  0xF>(best);  // quad_perm xor1
                best = dpp_max_f64<0x4E,  0xF>(best);  // quad_perm xor2
                best = dpp_max_f64<0x124, 0xF>(best);  // row_ror:4
                best = dpp_max_f64<0x128, 0xF>(best);  // row_ror:8
                best = dpp_max_f64<0x142, 0xA>(best);  // row_bcast15
                best = dpp_max_f64<0x143, 0xC>(best);  // row_bcast31

                const int pb = s & 1;
                if (lane == 63)
                    smem.f.rv64[pb][wave] = (ull)__double_as_longlong(best);
                __syncthreads();

                // cross-wave: read partial[lane&3], 2 DPP levels -> max of 4 waves
                double g = __longlong_as_double((long long)smem.f.rv64[pb][lane & 3]);
                g = dpp_max_f64<0xB1, 0xF>(g);
                g = dpp_max_f64<0x4E, 0xF>(g);
                cur = (int)~(unsigned)(ull)__double_as_longlong(g);
            }
        } else {
            // ---------------- publisher waves (4-7) ----------------
            // Per step: one barrier (pairs with the active waves' mid-step
            // barrier). Post-barrier at s%32==31, sel[base..s] is visible
            // (sel[s] written pre-barrier by t0; sxyz immutable).
            const int tt = t - PT;                  // 0..255, publish lanes 0..31
            for (int s = 0; s < NS; ++s) {
                __syncthreads();
                if ((s & 31) == 31) {
                    const int base = s - 31;
                    if (tt < 32) {
                        float4 p = smem.f.sxyz[smem.f.sel[base + tt]];
                        float* dst = out_coords + ((size_t)b * NS + base + tt) * 3;
                        dst[0] = p.x; dst[1] = p.y; dst[2] = p.z;
                    }
                    if (tt == 0)                    // release covers wave 4's stores
                        __hip_atomic_store(&flags[b * 16], (unsigned)((s + 1) >> 5),
                                           __ATOMIC_RELEASE, __HIP_MEMORY_SCOPE_AGENT);
                }
            }
        }
    } else {
        // ===== persistent worker: knn + fused gather/MLP/max per query =====
        const int wid = blockIdx.x - NB;           // 0..247
        const int c = t & 31;
        const int o = t & (DOUT - 1);
        const int grp = t >> 7;                    // 0..3
        const int lane = t & 63;

        for (int j = wid; j < NB * NS; j += NW) {
            const int s = j >> 3, b = j & 7;       // ascending s per worker
            const int q = b * NS + s;

            if (t == 0) {
                const unsigned need = (unsigned)(s >> 5) + 1;
                while (__hip_atomic_load(&flags[b * 16], __ATOMIC_ACQUIRE,
                                         __HIP_MEMORY_SCOPE_AGENT) < need)
                    __builtin_amdgcn_s_sleep(32);
            }
            __syncthreads();

            const float* cb = coords + (size_t)b * NP * 3;
            const float* qp = out_coords + (size_t)q * 3;
            const float qx = qp[0], qy = qp[1], qz = qp[2];

            for (int i = t; i < KBINS * 33; i += MT) ((unsigned*)smem.k.hist)[i] = 0;
            if (t == 0) smem.k.ccnt = 0;
            __syncthreads();

            for (int jj = 0; jj < KJ; ++jj) {
                int i = t + jj * MT;
                float dx = cb[i * 3 + 0] - qx, dy = cb[i * 3 + 1] - qy, dz = cb[i * 3 + 2] - qz;
                float d = fmaf(dz, dz, fmaf(dy, dy, dx * dx));
                smem.k.sdist[i] = d;
                atomicAdd(&smem.k.hist[knn_bin(d)][c], 1u);
            }
            __syncthreads();

            if (t < 64) {
                unsigned total = 0;
#pragma unroll
                for (int cc = 0; cc < 32; ++cc) total += smem.k.hist[t][cc];
                unsigned incl = total;
#pragma unroll
                for (int off = 1; off < 64; off <<= 1) {
                    unsigned n = __shfl_up(incl, off);
                    if (t >= off) incl += n;
                }
                unsigned excl = incl - total;
                if (excl < NK && incl >= NK) smem.k.cut = t;
            }
            __syncthreads();

            const int cut = smem.k.cut;
            for (int jj = 0; jj < KJ; ++jj) {
                int i = t + jj * MT;
                float d = smem.k.sdist[i];
                bool take = knn_bin(d) <= cut;
                unsigned long long mk = __ballot(take);
                unsigned base = 0;
                if (lane == 0 && mk)
                    base = atomicAdd(&smem.k.ccnt, (unsigned)__popcll(mk));
                base = __shfl(base, 0);
                if (take) {
                    unsigned p = base + (unsigned)__popcll(mk & ((1ull << lane) - 1ull));
                    if (p < MAXC) { smem.k.cd[p] = d; smem.k.ci[p] = i; }
                }
            }
            __syncthreads();

            // parallel rank-select: rank = #{(dj,ij) < (d,i)}; unique ranks -> LDS
            int cnt = (int)(smem.k.ccnt < (unsigned)MAXC ? smem.k.ccnt : (unsigned)MAXC);
            for (int p = t; p < cnt; p += MT) {
                float d = smem.k.cd[p]; int idx = smem.k.ci[p];
                int rank = 0;
                for (int jj = 0; jj < cnt; ++jj) {
                    float dj = smem.k.cd[jj]; int ij = smem.k.ci[jj];
                    rank += (dj < d || (dj == d && ij < idx)) ? 1 : 0;
                }
                if (rank < NK) smem.k.sidx[rank] = idx;
            }
            __syncthreads();

            // gather 16 neighbor feat rows (coalesced 256-B rows)
#pragma unroll
            for (int rr = 0; rr < 2; ++rr) {
                int row = (t >> 6) + rr * 8;       // 0..15
                smem.k.sf[row][t & 63] =
                    feat[((size_t)b * NP + smem.k.sidx[row]) * DIN + (t & 63)];
            }
            __syncthreads();

            // fused MLP+relu+max: each thread handles out-channel o, neighbors
            // {grp, grp+4, grp+8, grp+12}; cross-group max via LDS
            const float cb0 = Cb[o];
            float mx = -3.4e38f;
#pragma unroll
            for (int nn = 0; nn < 4; ++nn) {
                const float4* f4 = (const float4*)smem.k.sf[grp + nn * 4];
                float acc = cb0;
#pragma unroll
                for (int k4 = 0; k4 < DIN / 4; ++k4) {
                    float4 f = f4[k4];
                    acc = fmaf(f.x, Wt[(k4 * 4 + 0) * DOUT + o], acc);
                    acc = fmaf(f.y, Wt[(k4 * 4 + 1) * DOUT + o], acc);
                    acc = fmaf(f.z, Wt[(k4 * 4 + 2) * DOUT + o], acc);
                    acc = fmaf(f.w, Wt[(k4 * 4 + 3) * DOUT + o], acc);
                }
                mx = fmaxf(mx, fmaxf(acc, 0.0f));
            }
            smem.k.red[grp][o] = mx;
            __syncthreads();

            if (t < DOUT) {
                float v = fmaxf(fmaxf(smem.k.red[0][t], smem.k.red[1][t]),
                                fmaxf(smem.k.red[2][t], smem.k.red[3][t]));
                outF[(size_t)q * DOUT + t] = v;
            }
            __syncthreads();
        }
    }
}

extern "C" void kernel_launch(void* const* d_in, const int* in_sizes, int n_in,
                              void* d_out, int out_size, void* d_ws, size_t ws_size,
                              hipStream_t stream)
{
    const float* coords = (const float*)d_in[0];
    const float* feat   = (const float*)d_in[1];
    const float* W      = (const float*)d_in[2];
    const float* bias   = (const float*)d_in[3];
    const float* gamma  = (const float*)d_in[4];
    const float* beta   = (const float*)d_in[5];
    const float* rmean  = (const float*)d_in[6];
    const float* rvar   = (const float*)d_in[7];

    float* out_coords = (float*)d_out;                    // [8,2048,3]
    float* out_feat   = out_coords + (size_t)NB * NS * 3; // [8,2048,128]

    char* ws = (char*)d_ws;
    float*    Wt    = (float*)ws;                         // 32 KB
    float*    Cb    = (float*)(ws + 32768);               // 512 B
    unsigned* flags = (unsigned*)(ws + 40960);            // 8 flags, 64B apart

    hipMemsetAsync(flags, 0, 8 * 16 * sizeof(unsigned), stream);
    fold_weights_kernel<<<(DIN * DOUT + 255) / 256, 256, 0, stream>>>(
        W, bias, gamma, beta, rmean, rvar, Wt, Cb);
    mega_kernel<<<NB + NW, MT, 0, stream>>>(
        coords, out_coords, feat, Wt, Cb, out_feat, flags);
}

// Round 5
// 2067.765 us; speedup vs baseline: 1.3270x; 1.0356x over previous
//
#include <hip/hip_runtime.h>

#define NB   8
#define NP   8192
#define NS   2048
#define NK   16
#define DIN  64
#define DOUT 128
#define BN_EPS 1e-5f

#define MT   1024           // mega-kernel block size (16 waves)
#define NW   248            // worker blocks (grid = 8 fps + 248 workers = 256 CUs)
#define FP   (NP / MT)      // 8 fps points per thread
#define FW   (MT / 64)      // 16 waves
#define KJ   (NP / MT)      // 8 knn points per thread
#define KBINS 64
#define MAXC 512

typedef unsigned long long ull;

// ---------------- K0: fold BN into weights, transpose to [k][o] ----------------
__global__ void fold_weights_kernel(const float* __restrict__ W, const float* __restrict__ bias,
                                    const float* __restrict__ gamma, const float* __restrict__ beta,
                                    const float* __restrict__ rmean, const float* __restrict__ rvar,
                                    float* __restrict__ Wt, float* __restrict__ Cb)
{
    int i = blockIdx.x * 256 + threadIdx.x;
    if (i < DIN * DOUT) {
        int o = i & (DOUT - 1);
        int k = i >> 7;
        float sc = gamma[o] * rsqrtf(rvar[o] + BN_EPS);
        Wt[i] = W[o * DIN + k] * sc;            // Wt[k*128 + o]
        if (i < DOUT) {
            Cb[i] = (bias[i] - rmean[i]) * sc + beta[i];
        }
    }
}

// ---------------- f64-packed argmax helpers --------------------------------------
// packed u64 = (fp32 dist bits << 32) | ~idx, as double (sign bit 0 -> numeric
// order == u64 order): fmax == (max dist, tie -> min idx).
template<int CTRL, int RMASK>
__device__ __forceinline__ double dpp_max_f64(double v)
{
    unsigned long long u = (unsigned long long)__double_as_longlong(v);
    unsigned hi = (unsigned)(u >> 32), lo = (unsigned)u;
    unsigned th = (unsigned)__builtin_amdgcn_update_dpp((int)hi, (int)hi, CTRL, RMASK, 0xF, false);
    unsigned tl = (unsigned)__builtin_amdgcn_update_dpp((int)lo, (int)lo, CTRL, RMASK, 0xF, false);
    double o = __longlong_as_double((long long)(((unsigned long long)th << 32) | tl));
    return fmax(v, o);
}

__device__ __forceinline__ float max3f(float a, float b, float c)
{
    return fmaxf(fmaxf(a, b), c);   // clang fuses to v_max3_f32 (exact, associative)
}

__device__ __forceinline__ int knn_bin(float d)
{
    int e = (int)(__float_as_uint(d) >> 23) - 90;   // monotone, clamped octave bins
    return e < 0 ? 0 : (e > 63 ? 63 : e);
}

// ---------------- mega kernel: 8 fps producers + 248 persistent workers --------
struct FpsS {
    float4 sxyz[NP];                    // 128 KB, immutable after staging
    int sel[NS];                        // 8 KB
    unsigned long long rv64[2][FW];     // double-buffered wave partials
};
struct KnnS {
    float sdist[NP];                    // 32 KB
    unsigned hist[KBINS][33];           // [bin][c] +pad: atomic bank=(bin+c)%32, conflict-free
    float cd[MAXC];
    int   ci[MAXC];
    int   sidx[NK];
    float sf[NK][DIN];                  // 4 KB gathered feat rows
    float red[8][DOUT];                 // 4 KB cross-group max
    unsigned ccnt;
    int cut;
};
union MegaS { FpsS f; KnnS k; };
// union = ~140 KB -> 1 block/CU; grid 256 -> all blocks co-resident,
// so producer progress never depends on dispatch order (deadlock-safe).

__global__ __launch_bounds__(MT, 1)
void mega_kernel(const float* __restrict__ coords, float* __restrict__ out_coords,
                 const float* __restrict__ feat, const float* __restrict__ Wt,
                 const float* __restrict__ Cb, float* __restrict__ outF,
                 unsigned* __restrict__ flags)
{
#pragma clang fp contract(off)
    __shared__ MegaS smem;
    const int t = threadIdx.x;

    if (blockIdx.x < NB) {
        // ================= FPS producer (1 block per batch) =================
        // 16 waves (4/SIMD): co-resident waves pipeline the per-step serial
        // chain (rv64 read -> DPP -> sxyz[cur] read); r0's structure otherwise.
        const int b = blockIdx.x;
        const float* cb = coords + (size_t)b * NP * 3;

        for (int i = t; i < NP; i += MT)
            smem.f.sxyz[i] = make_float4(cb[i * 3 + 0], cb[i * 3 + 1], cb[i * 3 + 2], 0.0f);
        __syncthreads();

        float px[FP], py[FP], pz[FP], dist[FP];
#pragma unroll
        for (int k = 0; k < FP; ++k) {
            float4 p = smem.f.sxyz[t + k * MT];
            px[k] = p.x; py[k] = p.y; pz[k] = p.z;
            dist[k] = 1e10f;
        }

        const int wave = t >> 6, lane = t & 63;
        const unsigned nt = ~(unsigned)t;          // ~(t + k*MT) == nt - (k<<10)
        int cur = 0;

        for (int s = 0; s < NS; ++s) {
            if (t == 0) smem.f.sel[s] = cur;
            const float4 cc = smem.f.sxyz[cur];
            const float cx = cc.x, cy = cc.y, cz = cc.z;

            // min-dist update over 8 register-resident points
#pragma unroll
            for (int k = 0; k < FP; ++k) {
                float dx = px[k] - cx, dy = py[k] - cy, dz = pz[k] - cz;
                float d = fmaf(dz, dz, fmaf(dy, dy, dx * dx));
                dist[k] = fminf(dist[k], d);
            }
            // max of 8 via v_max3 tree (exact; max associative)
            float a0 = max3f(dist[0], dist[1], dist[2]);
            float a1 = max3f(dist[3], dist[4], dist[5]);
            float m  = max3f(a0, a1, fmaxf(dist[6], dist[7]));
            // recover smallest k attaining m (descending cndmask chain)
            int kk = 0;
#pragma unroll
            for (int k = FP - 1; k >= 0; --k)
                if (dist[k] == m) kk = k;
            double best = __longlong_as_double(
                (long long)(((ull)__float_as_uint(m) << 32) | (nt - (unsigned)(kk << 10))));

            // wave argmax: 6 DPP f64-max levels -> lane 63 holds wave max
            best = dpp_max_f64<0xB1,  0xF>(best);  // quad_perm xor1
            best = dpp_max_f64<0x4E,  0xF>(best);  // quad_perm xor2
            best = dpp_max_f64<0x124, 0xF>(best);  // row_ror:4
            best = dpp_max_f64<0x128, 0xF>(best);  // row_ror:8
            best = dpp_max_f64<0x142, 0xA>(best);  // row_bcast15
            best = dpp_max_f64<0x143, 0xC>(best);  // row_bcast31

            const int pb = s & 1;
            if (lane == 63) smem.f.rv64[pb][wave] = (ull)__double_as_longlong(best);
            __syncthreads();

            // cross-wave: b64 read of partial[lane&15], 4 DPP levels over row-of-16
            double g = __longlong_as_double((long long)smem.f.rv64[pb][lane & 15]);
            g = dpp_max_f64<0xB1,  0xF>(g);
            g = dpp_max_f64<0x4E,  0xF>(g);
            g = dpp_max_f64<0x124, 0xF>(g);
            g = dpp_max_f64<0x128, 0xF>(g);
            cur = (int)~(unsigned)(ull)__double_as_longlong(g);

            // publish a 32-query granule (wave 0 only: program-order release
            // covers the wave's own coord stores)
            if ((s & 31) == 31) {
                int base = s - 31;
                if (t < 32) {
                    float4 p = smem.f.sxyz[smem.f.sel[base + t]];
                    float* dst = out_coords + ((size_t)b * NS + base + t) * 3;
                    dst[0] = p.x; dst[1] = p.y; dst[2] = p.z;
                }
                if (t == 0)
                    __hip_atomic_store(&flags[b * 16], (unsigned)((s + 1) >> 5),
                                       __ATOMIC_RELEASE, __HIP_MEMORY_SCOPE_AGENT);
            }
        }
    } else {
        // ===== persistent worker: knn + fused gather/MLP/max per query =====
        const int wid = blockIdx.x - NB;           // 0..247
        const int c = t & 31;
        const int o = t & (DOUT - 1);
        const int grp = t >> 7;                    // 0..7
        const int lane = t & 63;

        for (int j = wid; j < NB * NS; j += NW) {
            const int s = j >> 3, b = j & 7;       // ascending s per worker
            const int q = b * NS + s;

            if (t == 0) {
                const unsigned need = (unsigned)(s >> 5) + 1;
                while (__hip_atomic_load(&flags[b * 16], __ATOMIC_ACQUIRE,
                                         __HIP_MEMORY_SCOPE_AGENT) < need)
                    __builtin_amdgcn_s_sleep(32);
            }
            __syncthreads();

            const float* cb = coords + (size_t)b * NP * 3;
            const float* qp = out_coords + (size_t)q * 3;
            const float qx = qp[0], qy = qp[1], qz = qp[2];

            for (int i = t; i < KBINS * 33; i += MT) ((unsigned*)smem.k.hist)[i] = 0;
            if (t == 0) smem.k.ccnt = 0;
            __syncthreads();

            for (int jj = 0; jj < KJ; ++jj) {
                int i = t + jj * MT;
                float dx = cb[i * 3 + 0] - qx, dy = cb[i * 3 + 1] - qy, dz = cb[i * 3 + 2] - qz;
                float d = fmaf(dz, dz, fmaf(dy, dy, dx * dx));
                smem.k.sdist[i] = d;
                atomicAdd(&smem.k.hist[knn_bin(d)][c], 1u);
            }
            __syncthreads();

            if (t < 64) {
                unsigned total = 0;
#pragma unroll
                for (int cc = 0; cc < 32; ++cc) total += smem.k.hist[t][cc];
                unsigned incl = total;
#pragma unroll
                for (int off = 1; off < 64; off <<= 1) {
                    unsigned n = __shfl_up(incl, off);
                    if (t >= off) incl += n;
                }
                unsigned excl = incl - total;
                if (excl < NK && incl >= NK) smem.k.cut = t;
            }
            __syncthreads();

            const int cut = smem.k.cut;
            for (int jj = 0; jj < KJ; ++jj) {
                int i = t + jj * MT;
                float d = smem.k.sdist[i];
                bool take = knn_bin(d) <= cut;
                unsigned long long mk = __ballot(take);
                unsigned base = 0;
                if (lane == 0 && mk)
                    base = atomicAdd(&smem.k.ccnt, (unsigned)__popcll(mk));
                base = __shfl(base, 0);
                if (take) {
                    unsigned p = base + (unsigned)__popcll(mk & ((1ull << lane) - 1ull));
                    if (p < MAXC) { smem.k.cd[p] = d; smem.k.ci[p] = i; }
                }
            }
            __syncthreads();

            // parallel rank-select: rank = #{(dj,ij) < (d,i)}; unique ranks -> LDS
            int cnt = (int)(smem.k.ccnt < (unsigned)MAXC ? smem.k.ccnt : (unsigned)MAXC);
            for (int p = t; p < cnt; p += MT) {
                float d = smem.k.cd[p]; int idx = smem.k.ci[p];
                int rank = 0;
                for (int jj = 0; jj < cnt; ++jj) {
                    float dj = smem.k.cd[jj]; int ij = smem.k.ci[jj];
                    rank += (dj < d || (dj == d && ij < idx)) ? 1 : 0;
                }
                if (rank < NK) smem.k.sidx[rank] = idx;
            }
            __syncthreads();

            // gather 16 neighbor feat rows (coalesced 256-B rows, single pass)
            {
                int row = t >> 6;                  // 0..15
                smem.k.sf[row][t & 63] =
                    feat[((size_t)b * NP + smem.k.sidx[row]) * DIN + (t & 63)];
            }
            __syncthreads();

            // fused MLP+relu+max: thread handles out-channel o, neighbors
            // {grp, grp+8}; cross-group max via LDS
            const float cb0 = Cb[o];
            float mx = -3.4e38f;
#pragma unroll
            for (int nn = 0; nn < 2; ++nn) {
                const float4* f4 = (const float4*)smem.k.sf[grp + nn * 8];
                float acc = cb0;
#pragma unroll
                for (int k4 = 0; k4 < DIN / 4; ++k4) {
                    float4 f = f4[k4];
                    acc = fmaf(f.x, Wt[(k4 * 4 + 0) * DOUT + o], acc);
                    acc = fmaf(f.y, Wt[(k4 * 4 + 1) * DOUT + o], acc);
                    acc = fmaf(f.z, Wt[(k4 * 4 + 2) * DOUT + o], acc);
                    acc = fmaf(f.w, Wt[(k4 * 4 + 3) * DOUT + o], acc);
                }
                mx = fmaxf(mx, fmaxf(acc, 0.0f));
            }
            smem.k.red[grp][o] = mx;
            __syncthreads();

            if (t < DOUT) {
                float v0 = max3f(smem.k.red[0][t], smem.k.red[1][t], smem.k.red[2][t]);
                float v1 = max3f(smem.k.red[3][t], smem.k.red[4][t], smem.k.red[5][t]);
                float v  = max3f(v0, v1, fmaxf(smem.k.red[6][t], smem.k.red[7][t]));
                outF[(size_t)q * DOUT + t] = v;
            }
            __syncthreads();
        }
    }
}

extern "C" void kernel_launch(void* const* d_in, const int* in_sizes, int n_in,
                              void* d_out, int out_size, void* d_ws, size_t ws_size,
                              hipStream_t stream)
{
    const float* coords = (const float*)d_in[0];
    const float* feat   = (const float*)d_in[1];
    const float* W      = (const float*)d_in[2];
    const float* bias   = (const float*)d_in[3];
    const float* gamma  = (const float*)d_in[4];
    const float* beta   = (const float*)d_in[5];
    const float* rmean  = (const float*)d_in[6];
    const float* rvar   = (const float*)d_in[7];

    float* out_coords = (float*)d_out;                    // [8,2048,3]
    float* out_feat   = out_coords + (size_t)NB * NS * 3; // [8,2048,128]

    char* ws = (char*)d_ws;
    float*    Wt    = (float*)ws;                         // 32 KB
    float*    Cb    = (float*)(ws + 32768);               // 512 B
    unsigned* flags = (unsigned*)(ws + 40960);            // 8 flags, 64B apart

    hipMemsetAsync(flags, 0, 8 * 16 * sizeof(unsigned), stream);
    fold_weights_kernel<<<(DIN * DOUT + 255) / 256, 256, 0, stream>>>(
        W, bias, gamma, beta, rmean, rvar, Wt, Cb);
    mega_kernel<<<NB + NW, MT, 0, stream>>>(
        coords, out_coords, feat, Wt, Cb, out_feat, flags);
}